// Round 4
// baseline (94.348 us; speedup 1.0000x reference)
//
#include <hip/hip_runtime.h>

#define FWHT_D 4096

typedef float v4f __attribute__((ext_vector_type(4)));

// LDS swizzle: XOR float-index bits 2..4 with bits 8..10. Bijective
// (source bits 8..10 are untouched). Bank math (32 banks x 4B):
//  W1/R2 (float4 at q*256+4L, fixed q): contiguous 1KiB ^ const -> conflict-free
//  R1/W2 (scalar at (L>>2)*256+4j+(L&3), fixed j): banks =
//         (L&3) | (((j^(L>>2))&7)<<2) -> 32 banks x 2-way -> free (m136)
static __device__ __forceinline__ int swz(int i) {
    return i ^ (((i >> 8) & 7) << 2);
}

static __device__ __forceinline__ void bfly(float& a, float& b) {
    float s = a + b;
    float d = a - b;
    a = s; b = d;
}

// One wave (64 threads) per row; 64 elements per lane; no cross-wave barriers.
__global__ __launch_bounds__(64, 2) void fwht_kernel(const float* __restrict__ x,
                                                     const float* __restrict__ signs,
                                                     float* __restrict__ out) {
    __shared__ float lds[FWHT_D];

    const int row = blockIdx.x;
    const int L   = threadIdx.x;                 // lane 0..63
    const float* xr  = x   + (size_t)row * FWHT_D;
    float*       orw = out + (size_t)row * FWHT_D;

    float v[64];

    // ---- Load: 16 nontemporal float4s, i = q*256 + 4L + e (1KiB/instr) ----
#pragma unroll
    for (int q = 0; q < 16; ++q) {
        v4f xv = __builtin_nontemporal_load((const v4f*)(xr + q * 256 + 4 * L));
        v[4 * q + 0] = xv.x; v[4 * q + 1] = xv.y;
        v[4 * q + 2] = xv.z; v[4 * q + 3] = xv.w;
    }
    // ---- Signs (cached; 16 KiB stays L1/L2-resident across blocks) ----
#pragma unroll
    for (int q = 0; q < 16; ++q) {
        v4f sv = *(const v4f*)(signs + q * 256 + 4 * L);
        v[4 * q + 0] *= sv.x; v[4 * q + 1] *= sv.y;
        v[4 * q + 2] *= sv.z; v[4 * q + 3] *= sv.w;
    }

    // ---- Phase 1: butterfly bits {0,1} (intra-quad) and {8..11} (q) ----
#pragma unroll
    for (int q = 0; q < 16; ++q) {
        bfly(v[4 * q + 0], v[4 * q + 1]);   // h = 1
        bfly(v[4 * q + 2], v[4 * q + 3]);
        bfly(v[4 * q + 0], v[4 * q + 2]);   // h = 2
        bfly(v[4 * q + 1], v[4 * q + 3]);
    }
#pragma unroll
    for (int pass = 0; pass < 4; ++pass) {  // h = 256, 512, 1024, 2048
        const int b = 1 << pass;
#pragma unroll
        for (int q = 0; q < 16; ++q) {
            if (!(q & b)) {
#pragma unroll
                for (int e = 0; e < 4; ++e)
                    bfly(v[4 * q + e], v[4 * (q | b) + e]);
            }
        }
    }

    // ---- W1: float4 -> LDS (swizzled) ----
#pragma unroll
    for (int q = 0; q < 16; ++q) {
        v4f p = { v[4 * q + 0], v[4 * q + 1], v[4 * q + 2], v[4 * q + 3] };
        *(v4f*)&lds[(q * 256 + 4 * L) ^ ((q & 7) << 2)] = p;
    }
    __syncthreads();   // single-wave: cheap; orders W1 -> R1 across lanes

    // ---- R1: lane owns i = (L>>2)*256 + 4j + (L&3), j = 0..63 ----
    const int hi = (L >> 2) * 256 + (L & 3);
    const int sx = ((L >> 2) & 7) << 2;
#pragma unroll
    for (int j = 0; j < 64; ++j)
        v[j] = lds[(hi + 4 * j) ^ sx];

    // ---- Phase 2: butterfly bits {2..7} = j bits 0..5 (h = 4..128) ----
#pragma unroll
    for (int pass = 0; pass < 6; ++pass) {
        const int b = 1 << pass;
#pragma unroll
        for (int j = 0; j < 64; ++j)
            if (!(j & b)) bfly(v[j], v[j | b]);
    }
    __syncthreads();   // orders R1 reads before W2 overwrite

    // ---- W2: scalar -> LDS (same swizzled addresses as R1) ----
#pragma unroll
    for (int j = 0; j < 64; ++j)
        lds[(hi + 4 * j) ^ sx] = v[j];
    __syncthreads();   // orders W2 -> R2 across lanes

    // ---- R2 + store: float4 at i = m*256 + 4L, coalesced 1KiB nt stores ----
#pragma unroll
    for (int m = 0; m < 16; ++m) {
        v4f p = *(const v4f*)&lds[(m * 256 + 4 * L) ^ ((m & 7) << 2)];
        __builtin_nontemporal_store(p, (v4f*)(orw + m * 256 + 4 * L));
    }
}

extern "C" void kernel_launch(void* const* d_in, const int* in_sizes, int n_in,
                              void* d_out, int out_size, void* d_ws, size_t ws_size,
                              hipStream_t stream) {
    const float* x     = (const float*)d_in[0];
    const float* signs = (const float*)d_in[1];
    float* out = (float*)d_out;

    const int rows = in_sizes[0] / FWHT_D;   // 16384 for the given shapes
    dim3 grid(rows), block(64);
    fwht_kernel<<<grid, block, 0, stream>>>(x, signs, out);
}

// Round 5
// 91.679 us; speedup vs baseline: 1.0291x; 1.0291x over previous
//
#include <hip/hip_runtime.h>

#define FWHT_D 4096

typedef float v4f __attribute__((ext_vector_type(4)));

// Involutive LDS swizzle: XOR float-index bits 2..4 with bits 6..8.
// Keeps 16B alignment (bits 0..1 untouched); conflict-free for all four
// access patterns below (0 LDS bank conflicts measured in R1).
static __device__ __forceinline__ int swz(int i) {
    return i ^ (((i >> 6) & 7) << 2);
}

static __device__ __forceinline__ void bfly(float& a, float& b) {
    float s = a + b;
    float d = a - b;
    a = s; b = d;
}

__global__ __launch_bounds__(256, 2) void fwht_kernel(const float* __restrict__ x,
                                                      const float* __restrict__ signs,
                                                      float* __restrict__ out) {
    __shared__ float lds[FWHT_D];

    const int row = blockIdx.x;
    const int t   = threadIdx.x;          // 0..255
    const float* xr  = x   + (size_t)row * FWHT_D;
    float*       orw = out + (size_t)row * FWHT_D;

    // ---------------- Phase 1: elements i = 1024k + 4t + e ----------------
    // Nontemporal float4 loads of x (read-once stream); signs stays cached.
    float r[4][4];
#pragma unroll
    for (int k = 0; k < 4; ++k) {
        const int i = 1024 * k + 4 * t;
        v4f xv = __builtin_nontemporal_load((const v4f*)(xr + i));
        v4f sv = *(const v4f*)(signs + i);
        v4f p  = xv * sv;
        r[k][0] = p.x; r[k][1] = p.y; r[k][2] = p.z; r[k][3] = p.w;
    }
#pragma unroll
    for (int k = 0; k < 4; ++k) {
        bfly(r[k][0], r[k][1]);   // h = 1
        bfly(r[k][2], r[k][3]);
        bfly(r[k][0], r[k][2]);   // h = 2
        bfly(r[k][1], r[k][3]);
    }
    // h = 1024 : k pairs (0,1),(2,3); h = 2048 : (0,2),(1,3)
#pragma unroll
    for (int pass = 0; pass < 2; ++pass) {
        const int b = 1 << pass;
#pragma unroll
        for (int k = 0; k < 4; ++k) {
            if (!(k & b)) {
#pragma unroll
                for (int e = 0; e < 4; ++e)
                    bfly(r[k][e], r[k | b][e]);
            }
        }
    }
    // Write to LDS (swizzled, 16B-aligned b128 stores).
#pragma unroll
    for (int k = 0; k < 4; ++k) {
        const int i = 1024 * k + 4 * t;
        v4f p = { r[k][0], r[k][1], r[k][2], r[k][3] };
        *(v4f*)&lds[swz(i)] = p;
    }
    __syncthreads();

    // ---------------- Phase 2: elements i = B*64 + 4j + c ----------------
    // B = t>>2 (0..63), c = t&3, j = 0..15 -> stages h = 4, 8, 16, 32.
    {
        const int B = t >> 2;
        const int c = t & 3;
        const int s = B & 7;            // == (i>>6)&7 for all j
        float v[16];
#pragma unroll
        for (int j = 0; j < 16; ++j)
            v[j] = lds[(B * 64 + 4 * j + c) ^ (s << 2)];

#pragma unroll
        for (int pass = 0; pass < 4; ++pass) {
            const int b = 1 << pass;    // j-bit -> h = 4<<pass
#pragma unroll
            for (int j = 0; j < 16; ++j)
                if (!(j & b)) bfly(v[j], v[j | b]);
        }

#pragma unroll
        for (int j = 0; j < 16; ++j)
            lds[(B * 64 + 4 * j + c) ^ (s << 2)] = v[j];
    }
    __syncthreads();

    // ---------------- Phase 3: elements i = w*1024 + 64j + l ----------------
    // w = t>>6, l = t&63, j = 0..15 -> stages h = 64, 128, 256, 512.
    {
        const int w = t >> 6;
        const int l = t & 63;
        float v[16];
#pragma unroll
        for (int j = 0; j < 16; ++j)
            v[j] = lds[(1024 * w + 64 * j + l) ^ ((j & 7) << 2)];

#pragma unroll
        for (int pass = 0; pass < 4; ++pass) {
            const int b = 1 << pass;    // j-bit -> h = 64<<pass
#pragma unroll
            for (int j = 0; j < 16; ++j)
                if (!(j & b)) bfly(v[j], v[j | b]);
        }

        // Coalesced nontemporal scalar stores (lane-consecutive per j).
#pragma unroll
        for (int j = 0; j < 16; ++j)
            __builtin_nontemporal_store(v[j], orw + 1024 * w + 64 * j + l);
    }
}

extern "C" void kernel_launch(void* const* d_in, const int* in_sizes, int n_in,
                              void* d_out, int out_size, void* d_ws, size_t ws_size,
                              hipStream_t stream) {
    const float* x     = (const float*)d_in[0];
    const float* signs = (const float*)d_in[1];
    float* out = (float*)d_out;

    const int rows = in_sizes[0] / FWHT_D;   // 16384 for the given shapes
    dim3 grid(rows), block(256);
    fwht_kernel<<<grid, block, 0, stream>>>(x, signs, out);
}